// Round 24
// baseline (276.224 us; speedup 1.0000x reference)
//
#include <hip/hip_runtime.h>
#include <hip/hip_bf16.h>

typedef __bf16 bf16_t;
typedef __attribute__((ext_vector_type(8))) __bf16 bf16x8;
typedef __attribute__((ext_vector_type(4))) float f32x4;
typedef __attribute__((ext_vector_type(16))) float f32x16;

__device__ __forceinline__ void gld_lds16(const void* g, void* l) {
  __builtin_amdgcn_global_load_lds((const __attribute__((address_space(1))) void*)g,
                                   (__attribute__((address_space(3))) void*)l, 16, 0, 0);
}

// ---------------------------------------------------------------- fused prep
// blocks [0, 24576): cast+concat -> Xcat[8192][3072] bf16
// blocks [24576, 32768): 8x weight transpose (f32 [k][n] -> bf16 [n][k])
__global__ __launch_bounds__(256) void prep_kernel(
    const float* __restrict__ w, const float* __restrict__ p,
    const float* __restrict__ c,
    const float* __restrict__ w_wq, const float* __restrict__ w_pq,
    const float* __restrict__ w_cq, const float* __restrict__ w_wk,
    const float* __restrict__ w_pk, const float* __restrict__ w_ck,
    const float* __restrict__ w_wv, const float* __restrict__ w_out,
    bf16_t* __restrict__ X, bf16_t* __restrict__ Wqkt,
    bf16_t* __restrict__ Wvt, bf16_t* __restrict__ Wot)
{
  __shared__ float t[32][33];
  const int bid = blockIdx.x, tid = threadIdx.x;
  if (bid < 24576) {
    unsigned idx = bid * 256u + tid;               // one 4-float chunk
    unsigned src = idx >> 21;                      // 2^21 chunks/source
    unsigned rem = idx & ((1u << 21) - 1);
    unsigned row = rem >> 8;
    unsigned k4  = (rem & 255u) * 4u;
    const float* s = (src == 0) ? w : (src == 1) ? p : c;
    f32x4 v = *(const f32x4*)(s + (size_t)row * 1024 + k4);
    ushort4 u;
    u.x = __builtin_bit_cast(unsigned short, (bf16_t)v[0]);
    u.y = __builtin_bit_cast(unsigned short, (bf16_t)v[1]);
    u.z = __builtin_bit_cast(unsigned short, (bf16_t)v[2]);
    u.w = __builtin_bit_cast(unsigned short, (bf16_t)v[3]);
    *(ushort4*)(X + (size_t)row * 3072 + src * 1024 + k4) = u;
  } else {
    const int tb = bid - 24576;                    // 8192 transpose blocks
    const int z = tb >> 10, rem = tb & 1023;
    const int by = rem >> 5, bx = rem & 31;
    const int tx = tid & 31, ty = tid >> 5;        // 32 x 8
    const float* src; bf16_t* dst; int dstride, koff, roff;
    switch (z) {
      case 0: src = w_wq;  dst = Wqkt; dstride = 3072; koff = 0;    roff = 0;    break;
      case 1: src = w_pq;  dst = Wqkt; dstride = 3072; koff = 1024; roff = 0;    break;
      case 2: src = w_cq;  dst = Wqkt; dstride = 3072; koff = 2048; roff = 0;    break;
      case 3: src = w_wk;  dst = Wqkt; dstride = 3072; koff = 0;    roff = 1024; break;
      case 4: src = w_pk;  dst = Wqkt; dstride = 3072; koff = 1024; roff = 1024; break;
      case 5: src = w_ck;  dst = Wqkt; dstride = 3072; koff = 2048; roff = 1024; break;
      case 6: src = w_wv;  dst = Wvt;  dstride = 1024; koff = 0;    roff = 0;    break;
      default: src = w_out; dst = Wot; dstride = 1024; koff = 0;    roff = 0;    break;
    }
    int x = bx * 32 + tx;
    int y0 = by * 32;
    for (int i = ty; i < 32; i += 8)
      t[i][tx] = src[(size_t)(y0 + i) * 1024 + x];
    __syncthreads();
    int n0 = bx * 32;
    for (int i = ty; i < 32; i += 8)
      dst[(size_t)(n0 + i + roff) * dstride + koff + y0 + tx] = (bf16_t)t[tx][i];
  }
}

// ---------------------------------------------------------------- fused QK + V GEMM (one dispatch)
// blocks [0,256): r20-validated 256x256 QK GEMM (4-phase, pre-barrier reads,
//   5 barriers/tile, vmcnt(4) counted, (r&7) XOR swizzle, 0 conflicts).
// blocks [256,512): r13-validated 128x256 V GEMM (2-phase, pre-barrier reads).
// Both depend only on prep; fusing removes a launch boundary and lets V
// blocks start on CUs whose QK block retires early. LDS sized for QK path.
__global__ __launch_bounds__(512, 2) void gemm_qkv(
    const bf16_t* __restrict__ Xc, const bf16_t* __restrict__ Wqkt,
    const bf16_t* __restrict__ Wvt, bf16_t* __restrict__ Qo,
    bf16_t* __restrict__ Ko, bf16_t* __restrict__ Vo, float scale)
{
  __shared__ bf16_t AsS[2][256 * 64];
  __shared__ bf16_t BsS[2][256 * 64];

  const int tid = threadIdx.x;
  const int wave = tid >> 6, lane = tid & 63;
  const int wm = wave >> 2, wn = wave & 3;      // 2 x 4 wave grid
  const int lrow = lane & 15, lch = lane >> 4;
  const int srow = tid >> 3, spp = tid & 7;

  if (blockIdx.x < 256) {
    // ------------------------- QK path (exact r20 body; nwg=256, nbx=8)
    const bf16_t* A  = Xc;  const int lda = 3072;
    const bf16_t* Bt = Wqkt; const int K = 3072;
    const int id  = blockIdx.x;
    const int swz = (id & 7) * 32 + (id >> 3);
    const int mb = swz >> 3, nb = swz & 7;
    const int m0 = mb * 256, n0 = nb * 256;

    auto STAGE_A = [&](int buf, int k0, int h) {
#pragma unroll
      for (int i = 0; i < 2; ++i) {
        int r = h * 128 + i * 64 + srow;
        int gsw = (spp ^ (r & 7)) * 8;          // pre-swizzled global source (rule #21)
        gld_lds16(A + (size_t)(m0 + r) * lda + k0 + gsw, &AsS[buf][r * 64 + spp * 8]);
      }
    };
    auto STAGE_B = [&](int buf, int k0, int h) {
#pragma unroll
      for (int i = 0; i < 2; ++i) {
        int r = h * 128 + i * 64 + srow;
        int gsw = (spp ^ (r & 7)) * 8;
        gld_lds16(Bt + (size_t)(n0 + r) * K + k0 + gsw, &BsS[buf][r * 64 + spp * 8]);
      }
    };

    const int NT = 48;
    STAGE_A(0, 0, 0); STAGE_A(0, 0, 1);
    STAGE_B(0, 0, 0); STAGE_B(0, 0, 1);
    STAGE_B(1, 64, 0); STAGE_B(1, 64, 1);
    asm volatile("s_waitcnt vmcnt(4)" ::: "memory"); // tile0 landed; tile1:B in flight
    asm volatile("s_barrier" ::: "memory");

    f32x4 acc[8][4] = {};

    for (int kt = 0; kt < NT; ++kt) {
      const int cur = kt & 1, nxt = cur ^ 1;
      bf16x8 bfr[4][2];                          // B frags, held across all 4 phases

#pragma unroll
      for (int p = 0; p < 4; ++p) {
        bf16x8 af[2][2];
#pragma unroll
        for (int j = 0; j < 2; ++j)
#pragma unroll
          for (int ks = 0; ks < 2; ++ks) {
            int r = wm * 128 + (p * 2 + j) * 16 + lrow;
            af[j][ks] = *(const bf16x8*)&AsS[cur][r * 64 + (((ks * 4 + lch) ^ (r & 7)) * 8)];
          }
        if (p == 0) {
#pragma unroll
          for (int n = 0; n < 4; ++n)
#pragma unroll
            for (int ks = 0; ks < 2; ++ks) {
              int r = wn * 64 + n * 16 + lrow;
              bfr[n][ks] = *(const bf16x8*)&BsS[cur][r * 64 + (((ks * 4 + lch) ^ (r & 7)) * 8)];
            }
        }
        if (p == 0 && kt + 1 < NT) STAGE_A(nxt, (kt + 1) * 64, 0);
        if (p == 1 && kt + 1 < NT) STAGE_A(nxt, (kt + 1) * 64, 1);
        if (p == 2 && kt + 2 < NT) STAGE_B(cur, (kt + 2) * 64, 0);
        if (p == 3 && kt + 2 < NT) STAGE_B(cur, (kt + 2) * 64, 1);
        if (p == 3) {
          if (kt + 2 < NT)      asm volatile("s_waitcnt vmcnt(4)" ::: "memory");
          else                  asm volatile("s_waitcnt vmcnt(0)" ::: "memory");
        }
        asm volatile("s_barrier" ::: "memory");
        __builtin_amdgcn_s_setprio(1);
#pragma unroll
        for (int ks = 0; ks < 2; ++ks)
#pragma unroll
          for (int j = 0; j < 2; ++j)
#pragma unroll
            for (int n = 0; n < 4; ++n)
              acc[p * 2 + j][n] = __builtin_amdgcn_mfma_f32_16x16x32_bf16(
                  af[j][ks], bfr[n][ks], acc[p * 2 + j][n], 0, 0, 0);
        __builtin_amdgcn_s_setprio(0);
        if (p == 3)                                  // only load-bearing barrier2:
          asm volatile("s_barrier" ::: "memory");    // guards next-tile As overwrite
      }
    }

    // epilogue: Q (scaled, cols<1024) / K (cols>=1024) to [B,H,N,D]
    const int g = lane >> 4, cl = lane & 15;
#pragma unroll
    for (int m = 0; m < 8; ++m) {
      int m_base = m0 + wm * 128 + m * 16 + g * 4;
      int bb = m_base >> 11, nn = m_base & 2047;
#pragma unroll
      for (int n = 0; n < 4; ++n) {
        int col = n0 + wn * 64 + n * 16 + cl;
        bf16_t* dst = (col < 1024) ? Qo : Ko;
        int cc2 = col & 1023;
        float sc = (col < 1024) ? scale : 1.0f;
        int h = cc2 >> 6, d = cc2 & 63;
        size_t base = ((size_t)(bb * 16 + h) * 2048 + nn) * 64 + d;
#pragma unroll
        for (int r = 0; r < 4; ++r)
          dst[base + (size_t)r * 64] = (bf16_t)(acc[m][n][r] * sc);
      }
    }
  } else {
    // ------------------------- V path (exact r13 gemm128x256<1> body)
    const bf16_t* A  = Xc;  const int lda = 3072;
    const bf16_t* Bt = Wvt; const int K = 1024;
    const int id  = blockIdx.x - 256;            // 256 blocks; 256%8==0 keeps XCD map
    const int swz = (id & 7) * 32 + (id >> 3);
    const int mb = swz >> 2, nb = swz & 3;       // nbx = 4
    const int m0 = mb * 128, n0 = nb * 256;

    auto STAGE_A = [&](int buf, int k0, int h) {
      int r = h * 64 + srow;
      int gsw = (spp ^ (r & 7)) * 8;
      gld_lds16(A + (size_t)(m0 + r) * lda + k0 + gsw, &AsS[buf][r * 64 + spp * 8]);
    };
    auto STAGE_B = [&](int buf, int k0, int h) {
#pragma unroll
      for (int i = 0; i < 2; ++i) {
        int r = h * 128 + i * 64 + srow;
        int gsw = (spp ^ (r & 7)) * 8;
        gld_lds16(Bt + (size_t)(n0 + r) * K + k0 + gsw, &BsS[buf][r * 64 + spp * 8]);
      }
    };

    const int NT = 16;
    STAGE_A(0, 0, 0); STAGE_A(0, 0, 1);
    STAGE_B(0, 0, 0); STAGE_B(0, 0, 1);
    STAGE_B(1, 64, 0); STAGE_B(1, 64, 1);
    asm volatile("s_waitcnt vmcnt(4)" ::: "memory");
    asm volatile("s_barrier" ::: "memory");

    f32x4 acc[4][4] = {};

    for (int kt = 0; kt < NT; ++kt) {
      const int cur = kt & 1, nxt = cur ^ 1;
      bf16x8 bfr[4][2];

#pragma unroll
      for (int p = 0; p < 2; ++p) {
        bf16x8 af[2][2];
#pragma unroll
        for (int j = 0; j < 2; ++j)
#pragma unroll
          for (int ks = 0; ks < 2; ++ks) {
            int r = wm * 64 + (p * 2 + j) * 16 + lrow;
            af[j][ks] = *(const bf16x8*)&AsS[cur][r * 64 + (((ks * 4 + lch) ^ (r & 7)) * 8)];
          }
        if (p == 0) {
#pragma unroll
          for (int n = 0; n < 4; ++n)
#pragma unroll
            for (int ks = 0; ks < 2; ++ks) {
              int r = wn * 64 + n * 16 + lrow;
              bfr[n][ks] = *(const bf16x8*)&BsS[cur][r * 64 + (((ks * 4 + lch) ^ (r & 7)) * 8)];
            }
        }
        if (p == 0 && kt + 1 < NT) { STAGE_A(nxt, (kt + 1) * 64, 0); STAGE_A(nxt, (kt + 1) * 64, 1); }
        if (p == 1 && kt + 2 < NT) { STAGE_B(cur, (kt + 2) * 64, 0); STAGE_B(cur, (kt + 2) * 64, 1); }
        if (p == 1) {
          if (kt + 2 < NT)      asm volatile("s_waitcnt vmcnt(4)" ::: "memory");
          else                  asm volatile("s_waitcnt vmcnt(0)" ::: "memory");
        }
        asm volatile("s_barrier" ::: "memory");
        __builtin_amdgcn_s_setprio(1);
#pragma unroll
        for (int ks = 0; ks < 2; ++ks)
#pragma unroll
          for (int j = 0; j < 2; ++j)
#pragma unroll
            for (int n = 0; n < 4; ++n)
              acc[p * 2 + j][n] = __builtin_amdgcn_mfma_f32_16x16x32_bf16(
                  af[j][ks], bfr[n][ks], acc[p * 2 + j][n], 0, 0, 0);
        __builtin_amdgcn_s_setprio(0);
        asm volatile("s_barrier" ::: "memory");
      }
    }

    // epilogue: V^T [B,H,D,N] bf16 packed
    const int g = lane >> 4, cl = lane & 15;
#pragma unroll
    for (int m = 0; m < 4; ++m) {
      int m_base = m0 + wm * 64 + m * 16 + g * 4;
      int bb = m_base >> 11, nn = m_base & 2047;
#pragma unroll
      for (int n = 0; n < 4; ++n) {
        int col = n0 + wn * 64 + n * 16 + cl;
        int h = col >> 6, d = col & 63;
        ushort4 u;
        u.x = __builtin_bit_cast(unsigned short, (bf16_t)acc[m][n][0]);
        u.y = __builtin_bit_cast(unsigned short, (bf16_t)acc[m][n][1]);
        u.z = __builtin_bit_cast(unsigned short, (bf16_t)acc[m][n][2]);
        u.w = __builtin_bit_cast(unsigned short, (bf16_t)acc[m][n][3]);
        *(ushort4*)(Vo + ((size_t)(bb * 16 + h) * 64 + d) * 2048 + nn) = u;
      }
    }
  }
}

// ---------------------------------------------------------------- GEMM 128x256 (B^T), 2-phase pre-barrier (r13-validated; out-proj)
__global__ __launch_bounds__(512, 2) void gemm_out(
    const bf16_t* __restrict__ A, int lda,
    const bf16_t* __restrict__ Bt, int K,
    float* __restrict__ Co, const float* __restrict__ bias)
{
  __shared__ bf16_t As[2][128 * 64];
  __shared__ bf16_t Bs[2][256 * 64];

  const int tid = threadIdx.x;
  const int wave = tid >> 6, lane = tid & 63;
  const int wm = wave >> 2, wn = wave & 3;      // 2 x 4 wave grid, per-wave 64x64
  const int lrow = lane & 15, lch = lane >> 4;

  const int nwg = gridDim.x, cpx = nwg >> 3;    // 256 blocks -> cpx=32
  const int id  = blockIdx.x;
  const int swz = (id & 7) * cpx + (id >> 3);
  const int mb = swz >> 2, nb = swz & 3;        // nbx = 4
  const int m0 = mb * 128, n0 = nb * 256;

  const int srow = tid >> 3, spp = tid & 7;

  auto STAGE_A = [&](int buf, int k0, int h) {
    int r = h * 64 + srow;
    int gsw = (spp ^ (r & 7)) * 8;
    gld_lds16(A + (size_t)(m0 + r) * lda + k0 + gsw, &As[buf][r * 64 + spp * 8]);
  };
  auto STAGE_B = [&](int buf, int k0, int h) {
#pragma unroll
    for (int i = 0; i < 2; ++i) {
      int r = h * 128 + i * 64 + srow;
      int gsw = (spp ^ (r & 7)) * 8;
      gld_lds16(Bt + (size_t)(n0 + r) * K + k0 + gsw, &Bs[buf][r * 64 + spp * 8]);
    }
  };

  const int NT = K >> 6;                        // 16 for K=1024
  STAGE_A(0, 0, 0); STAGE_A(0, 0, 1);
  STAGE_B(0, 0, 0); STAGE_B(0, 0, 1);
  STAGE_B(1, 64, 0); STAGE_B(1, 64, 1);
  asm volatile("s_waitcnt vmcnt(4)" ::: "memory");
  asm volatile("s_barrier" ::: "memory");

  f32x4 acc[4][4] = {};

  for (int kt = 0; kt < NT; ++kt) {
    const int cur = kt & 1, nxt = cur ^ 1;
    bf16x8 bfr[4][2];

#pragma unroll
    for (int p = 0; p < 2; ++p) {
      bf16x8 af[2][2];
#pragma unroll
      for (int j = 0; j < 2; ++j)
#pragma unroll
        for (int ks = 0; ks < 2; ++ks) {
          int r = wm * 64 + (p * 2 + j) * 16 + lrow;
          af[j][ks] = *(const bf16x8*)&As[cur][r * 64 + (((ks * 4 + lch) ^ (r & 7)) * 8)];
        }
      if (p == 0) {
#pragma unroll
        for (int n = 0; n < 4; ++n)
#pragma unroll
          for (int ks = 0; ks < 2; ++ks) {
            int r = wn * 64 + n * 16 + lrow;
            bfr[n][ks] = *(const bf16x8*)&Bs[cur][r * 64 + (((ks * 4 + lch) ^ (r & 7)) * 8)];
          }
      }
      if (p == 0 && kt + 1 < NT) { STAGE_A(nxt, (kt + 1) * 64, 0); STAGE_A(nxt, (kt + 1) * 64, 1); }
      if (p == 1 && kt + 2 < NT) { STAGE_B(cur, (kt + 2) * 64, 0); STAGE_B(cur, (kt + 2) * 64, 1); }
      if (p == 1) {
        if (kt + 2 < NT)      asm volatile("s_waitcnt vmcnt(4)" ::: "memory");
        else                  asm volatile("s_waitcnt vmcnt(0)" ::: "memory");
      }
      asm volatile("s_barrier" ::: "memory");
      __builtin_amdgcn_s_setprio(1);
#pragma unroll
      for (int ks = 0; ks < 2; ++ks)
#pragma unroll
        for (int j = 0; j < 2; ++j)
#pragma unroll
          for (int n = 0; n < 4; ++n)
            acc[p * 2 + j][n] = __builtin_amdgcn_mfma_f32_16x16x32_bf16(
                af[j][ks], bfr[n][ks], acc[p * 2 + j][n], 0, 0, 0);
      __builtin_amdgcn_s_setprio(0);
      asm volatile("s_barrier" ::: "memory");
    }
  }

  const int g = lane >> 4, cl = lane & 15;
#pragma unroll
  for (int m = 0; m < 4; ++m) {
    int m_base = m0 + wm * 64 + m * 16 + g * 4;
#pragma unroll
    for (int n = 0; n < 4; ++n) {
      int col = n0 + wn * 64 + n * 16 + cl;
      float bv = bias[col];
#pragma unroll
      for (int r = 0; r < 4; ++r)
        Co[(size_t)(m_base + r) * 1024 + col] = acc[m][n][r] + bv;
    }
  }
}

// ---------------------------------------------------------------- attention v5.3 (r19/r20-validated; register-bound floor)
__global__ __launch_bounds__(256, 2) void attn_kernel(
    const bf16_t* __restrict__ Q, const bf16_t* __restrict__ Kb,
    const bf16_t* __restrict__ Vt, bf16_t* __restrict__ O)
{
  __shared__ bf16_t Ks[2][64 * 64];
  __shared__ bf16_t Vs[2][64 * 64];

  const int fid = blockIdx.x;
  const int swz = (fid & 7) * 64 + (fid >> 3);
  const int bh = swz >> 3, qt = swz & 7;
  const int bb = bh >> 4, h = bh & 15;

  const int tid = threadIdx.x, wave = tid >> 6, lane = tid & 63;
  const int lq = lane & 31;
  const int lh = lane >> 5;

  const bf16_t* Qb    = Q  + ((size_t)bh * 2048 + qt * 256) * 64;
  const bf16_t* Kbase = Kb + (size_t)bh * 2048 * 64;
  const bf16_t* Vbase = Vt + (size_t)bh * 64 * 2048;

  const int srow = tid >> 3, spp = tid & 7;      // 32 rows x 8 granules per instr

  auto STAGE_K = [&](int buf, int tile) {
#pragma unroll
    for (int i = 0; i < 2; ++i) {
      int r = i * 32 + srow;
      int sg = (spp ^ (r & 7)) * 8;              // pre-swizzled source (rule #21)
      gld_lds16(Kbase + (size_t)(tile * 64 + r) * 64 + sg, &Ks[buf][i * 2048 + tid * 8]);
    }
  };
  auto STAGE_V = [&](int buf, int tile) {
#pragma unroll
    for (int i = 0; i < 2; ++i) {
      int r = i * 32 + srow;
      int sg = (spp ^ (r & 7)) * 8;
      gld_lds16(Vbase + (size_t)r * 2048 + tile * 64 + sg, &Vs[buf][i * 2048 + tid * 8]);
    }
  };

  // prologue staging: K0, V0, K1 (6 loads)
  STAGE_K(0, 0); STAGE_V(0, 0); STAGE_K(1, 1);

  // Q fragments, two q-blocks per wave (scale*log2e folded into Q buffer)
  bf16x8 qf0[4], qf1[4];
#pragma unroll
  for (int kf = 0; kf < 4; ++kf) {
    qf0[kf] = *(const bf16x8*)(Qb + (size_t)(wave * 64 + lq) * 64 + kf * 16 + lh * 8);
    qf1[kf] = *(const bf16x8*)(Qb + (size_t)(wave * 64 + 32 + lq) * 64 + kf * 16 + lh * 8);
  }

  f32x16 acc0[2] = {}, acc1[2] = {};
  float m0r = -1.0e30f, l0r = 0.f, m1r = -1.0e30f, l1r = 0.f;
  bf16x8 pb0[4], pb1[4];

  auto QKT2 = [&](int tile, f32x16 (&s0)[2], f32x16 (&s1)[2]) {
    const int kb = tile & 1;
#pragma unroll
    for (int nb2 = 0; nb2 < 2; ++nb2) {
      int r = nb2 * 32 + lq;
      f32x16 z0 = {}, z1 = {};
#pragma unroll
      for (int kf = 0; kf < 4; ++kf) {
        bf16x8 ka = *(const bf16x8*)&Ks[kb][r * 64 + (((kf * 2 + lh) ^ (r & 7)) * 8)];
        z0 = __builtin_amdgcn_mfma_f32_32x32x16_bf16(ka, qf0[kf], z0, 0, 0, 0);
        z1 = __builtin_amdgcn_mfma_f32_32x32x16_bf16(ka, qf1[kf], z1, 0, 0, 0);
      }
      s0[nb2] = z0; s1[nb2] = z1;
    }
  };

  auto PV2 = [&](int tile) {
    const int vb = tile & 1;
#pragma unroll
    for (int ks = 0; ks < 4; ++ks)
#pragma unroll
      for (int db = 0; db < 2; ++db) {
        int r = db * 32 + lq;
        bf16x8 va = *(const bf16x8*)&Vs[vb][r * 64 + (((ks * 2 + lh) ^ (r & 7)) * 8)];
        acc0[db] = __builtin_amdgcn_mfma_f32_32x32x16_bf16(va, pb0[ks], acc0[db], 0, 0, 0);
        acc1[db] = __builtin_amdgcn_mfma_f32_32x32x16_bf16(va, pb1[ks], acc1[db], 0, 0, 0);
      }
  };

  auto SOFTMAX = [&](f32x16 (&st)[2], float& mr, float& lr,
                     f32x16 (&ac)[2], bf16x8 (&po)[4]) {
    float tmax = fmaxf(st[0][0], st[0][1]);
#pragma unroll
    for (int nb2 = 0; nb2 < 2; ++nb2)
#pragma unroll
      for (int rg = (nb2 ? 0 : 2); rg < 16; rg += 2)
        tmax = fmaxf(fmaxf(tmax, st[nb2][rg]), st[nb2][rg + 1]);
    tmax = fmaxf(tmax, __shfl_xor(tmax, 32));    // column max (needed per-iter)

    if (!__all(tmax <= mr + 8.0f)) {             // defer-rescale (T13)
      float mnew = fmaxf(mr, tmax);
      float corr = __builtin_amdgcn_exp2f(mr - mnew);
      mr = mnew;
      lr *= corr;
#pragma unroll
      for (int db = 0; db < 2; ++db)
#pragma unroll
        for (int rg = 0; rg < 16; ++rg)
          ac[db][rg] *= corr;
    }

    float sm = 0.f;
#pragma unroll
    for (int nb2 = 0; nb2 < 2; ++nb2)
#pragma unroll
      for (int rg = 0; rg < 16; ++rg) {
        float p = __builtin_amdgcn_exp2f(st[nb2][rg] - mr);
        st[nb2][rg] = p;
        sm += p;
      }
    lr += sm;                                    // per-lane half-row partial;
                                                 // cross-half reduce deferred

    // pack P (T12: cvt_pk + permlane32_swap)
#pragma unroll
    for (int ks = 0; ks < 4; ++ks) {
      const int nb2 = ks >> 1;
      const int R = (ks & 1) * 8;
      unsigned x0, x1, y0, y1;
      asm("v_cvt_pk_bf16_f32 %0, %1, %2" : "=v"(x0) : "v"(st[nb2][R + 0]), "v"(st[nb2][R + 1]));
      asm("v_cvt_pk_bf16_f32 %0, %1, %2" : "=v"(x1) : "v"(st[nb2][R + 2]), "v"(st[nb2][R + 3]));
      asm("v_cvt_pk_bf16_f32 %0, %1, %2" : "=v"(y0) : "v"(st[nb2][R + 4]), "v"(st[nb2][R + 5]));
      asm("v_cvt_pk_bf16_f32 %0, %1, %2" : "=v"(y1) : "v"(st[nb2][R + 6]), "v"(st[nb2][R + 7]));
      asm volatile("v_permlane32_swap_b32 %0, %1" : "+v"(x0), "+v"(y0));
      asm volatile("v_permlane32_swap_b32 %0, %1" : "+v"(x1), "+v"(y1));
      int4 pw;
      pw.x = (int)x0; pw.y = (int)x1; pw.z = (int)y0; pw.w = (int)y1;
      po[ks] = __builtin_bit_cast(bf16x8, pw);
    }
  };

  // prologue compute: S(0) -> softmax -> pb(0); FULL vmcnt drain (r9 lesson)
  asm volatile("s_waitcnt vmcnt(0)" ::: "memory");
  __builtin_amdgcn_s_barrier();
  asm volatile("" ::: "memory");
  {
    f32x16 s0[2], s1[2];
    QKT2(0, s0, s1);
    SOFTMAX(s0, m0r, l0r, acc0, pb0);
    SOFTMAX(s1, m1r, l1r, acc1, pb1);
  }
  asm volatile("s_waitcnt lgkmcnt(0)" ::: "memory");  // my Ks[0] reads done
  __builtin_amdgcn_s_barrier();                       // before iter0 restages Ks[0]
  asm volatile("" ::: "memory");

  for (int t = 0; t < 32; ++t) {
    if (t < 30)       { STAGE_V((t + 1) & 1, t + 1); STAGE_K(t & 1, t + 2); }
    else if (t == 30) { STAGE_V(1, 31); }
    if (t < 30)       asm volatile("s_waitcnt vmcnt(4)" ::: "memory"); // V(t),K(t+1) landed
    else if (t == 30) asm volatile("s_waitcnt vmcnt(2)" ::: "memory");
    else              asm volatile("s_waitcnt vmcnt(0)" ::: "memory");
    __builtin_amdgcn_s_barrier();
    asm volatile("" ::: "memory");

    f32x16 s0[2], s1[2];
    __builtin_amdgcn_s_setprio(1);
    if (t < 31) QKT2(t + 1, s0, s1);   // MFMA, independent of pb
    PV2(t);                            // MFMA, uses pb from previous softmax
    __builtin_amdgcn_s_setprio(0);
    if (t < 31) {
      SOFTMAX(s0, m0r, l0r, acc0, pb0);
      SOFTMAX(s1, m1r, l1r, acc1, pb1);
    }

    asm volatile("s_waitcnt lgkmcnt(0)" ::: "memory");
    __builtin_amdgcn_s_barrier();
    asm volatile("" ::: "memory");
  }

  // epilogue: cross-half sum reduce (once), normalize, write O[B,N,H*D]
  float l0t = l0r + __shfl_xor(l0r, 32);
  float l1t = l1r + __shfl_xor(l1r, 32);
  float inv0 = 1.0f / l0t, inv1 = 1.0f / l1t;
#pragma unroll
  for (int qb = 0; qb < 2; ++qb) {
    float inv = qb ? inv1 : inv0;
    int nn = qt * 256 + wave * 64 + qb * 32 + lq;
    size_t obase = ((size_t)bb * 2048 + nn) * 1024 + h * 64;
#pragma unroll
    for (int db = 0; db < 2; ++db)
#pragma unroll
      for (int rr = 0; rr < 4; ++rr) {
        f32x16& a = qb ? acc1[db] : acc0[db];
        ushort4 u;
        u.x = __builtin_bit_cast(unsigned short, (bf16_t)(a[rr * 4 + 0] * inv));
        u.y = __builtin_bit_cast(unsigned short, (bf16_t)(a[rr * 4 + 1] * inv));
        u.z = __builtin_bit_cast(unsigned short, (bf16_t)(a[rr * 4 + 2] * inv));
        u.w = __builtin_bit_cast(unsigned short, (bf16_t)(a[rr * 4 + 3] * inv));
        *(ushort4*)(O + obase + db * 32 + rr * 8 + lh * 4) = u;
      }
  }
}

// ---------------------------------------------------------------- launch
extern "C" void kernel_launch(void* const* d_in, const int* in_sizes, int n_in,
                              void* d_out, int out_size, void* d_ws, size_t ws_size,
                              hipStream_t stream) {
  const float* words     = (const float*)d_in[0];
  const float* position  = (const float*)d_in[1];
  const float* conscious = (const float*)d_in[2];
  const float* w_wq  = (const float*)d_in[3];
  const float* w_wk  = (const float*)d_in[4];
  const float* w_wv  = (const float*)d_in[5];
  const float* w_pq  = (const float*)d_in[6];
  const float* w_pk  = (const float*)d_in[7];
  const float* w_cq  = (const float*)d_in[8];
  const float* w_ck  = (const float*)d_in[9];
  const float* w_out = (const float*)d_in[10];
  const float* b_out = (const float*)d_in[11];

  char* ws = (char*)d_ws;
  bf16_t* Xcat = (bf16_t*)(ws);                 // 48 MiB [8192][3072]
  bf16_t* Wqkt = (bf16_t*)(ws + 50331648);      // 12 MiB [2048][3072]
  bf16_t* Wvt  = (bf16_t*)(ws + 62914560);      // 2 MiB  [1024][1024]
  bf16_t* Wot  = (bf16_t*)(ws + 65011712);      // 2 MiB  [1024][1024]
  bf16_t* Qb   = (bf16_t*)(ws + 67108864);      // 16 MiB [B,H,N,D]
  bf16_t* Kbf  = (bf16_t*)(ws + 83886080);      // 16 MiB [B,H,N,D]
  bf16_t* Vtb  = (bf16_t*)(ws + 100663296);     // 16 MiB [B,H,D,N]
  bf16_t* Ob   = (bf16_t*)(ws + 117440512);     // 16 MiB [B,N,H*D]

  // fused cast+concat + weight transposes (one dispatch, shared BW)
  prep_kernel<<<32768, 256, 0, stream>>>(words, position, conscious,
      w_wq, w_pq, w_cq, w_wk, w_pk, w_ck, w_wv, w_out, Xcat, Wqkt, Wvt, Wot);

  // fused QK (blocks 0-255) + V (blocks 256-511) GEMM, one dispatch
  gemm_qkv<<<512, 512, 0, stream>>>(Xcat, Wqkt, Wvt, Qb, Kbf, Vtb,
                                    0.125f * 1.44269504f);

  attn_kernel<<<512, 256, 0, stream>>>(Qb, Kbf, Vtb, Ob);

  // out GEMM: 128x256 tiles, f32 + bias
  gemm_out<<<256, 512, 0, stream>>>(Ob, 1024, Wot, 1024, (float*)d_out, b_out);
}

// Round 25
// 265.156 us; speedup vs baseline: 1.0417x; 1.0417x over previous
//
#include <hip/hip_runtime.h>
#include <hip/hip_bf16.h>

typedef __bf16 bf16_t;
typedef __attribute__((ext_vector_type(8))) __bf16 bf16x8;
typedef __attribute__((ext_vector_type(4))) float f32x4;
typedef __attribute__((ext_vector_type(16))) float f32x16;

__device__ __forceinline__ void gld_lds16(const void* g, void* l) {
  __builtin_amdgcn_global_load_lds((const __attribute__((address_space(1))) void*)g,
                                   (__attribute__((address_space(3))) void*)l, 16, 0, 0);
}

// ---------------------------------------------------------------- fused prep
// blocks [0, 24576): cast+concat -> Xcat[8192][3072] bf16
// blocks [24576, 32768): 8x weight transpose (f32 [k][n] -> bf16 [n][k])
__global__ __launch_bounds__(256) void prep_kernel(
    const float* __restrict__ w, const float* __restrict__ p,
    const float* __restrict__ c,
    const float* __restrict__ w_wq, const float* __restrict__ w_pq,
    const float* __restrict__ w_cq, const float* __restrict__ w_wk,
    const float* __restrict__ w_pk, const float* __restrict__ w_ck,
    const float* __restrict__ w_wv, const float* __restrict__ w_out,
    bf16_t* __restrict__ X, bf16_t* __restrict__ Wqkt,
    bf16_t* __restrict__ Wvt, bf16_t* __restrict__ Wot)
{
  __shared__ float t[32][33];
  const int bid = blockIdx.x, tid = threadIdx.x;
  if (bid < 24576) {
    unsigned idx = bid * 256u + tid;               // one 4-float chunk
    unsigned src = idx >> 21;                      // 2^21 chunks/source
    unsigned rem = idx & ((1u << 21) - 1);
    unsigned row = rem >> 8;
    unsigned k4  = (rem & 255u) * 4u;
    const float* s = (src == 0) ? w : (src == 1) ? p : c;
    f32x4 v = *(const f32x4*)(s + (size_t)row * 1024 + k4);
    ushort4 u;
    u.x = __builtin_bit_cast(unsigned short, (bf16_t)v[0]);
    u.y = __builtin_bit_cast(unsigned short, (bf16_t)v[1]);
    u.z = __builtin_bit_cast(unsigned short, (bf16_t)v[2]);
    u.w = __builtin_bit_cast(unsigned short, (bf16_t)v[3]);
    *(ushort4*)(X + (size_t)row * 3072 + src * 1024 + k4) = u;
  } else {
    const int tb = bid - 24576;                    // 8192 transpose blocks
    const int z = tb >> 10, rem = tb & 1023;
    const int by = rem >> 5, bx = rem & 31;
    const int tx = tid & 31, ty = tid >> 5;        // 32 x 8
    const float* src; bf16_t* dst; int dstride, koff, roff;
    switch (z) {
      case 0: src = w_wq;  dst = Wqkt; dstride = 3072; koff = 0;    roff = 0;    break;
      case 1: src = w_pq;  dst = Wqkt; dstride = 3072; koff = 1024; roff = 0;    break;
      case 2: src = w_cq;  dst = Wqkt; dstride = 3072; koff = 2048; roff = 0;    break;
      case 3: src = w_wk;  dst = Wqkt; dstride = 3072; koff = 0;    roff = 1024; break;
      case 4: src = w_pk;  dst = Wqkt; dstride = 3072; koff = 1024; roff = 1024; break;
      case 5: src = w_ck;  dst = Wqkt; dstride = 3072; koff = 2048; roff = 1024; break;
      case 6: src = w_wv;  dst = Wvt;  dstride = 1024; koff = 0;    roff = 0;    break;
      default: src = w_out; dst = Wot; dstride = 1024; koff = 0;    roff = 0;    break;
    }
    int x = bx * 32 + tx;
    int y0 = by * 32;
    for (int i = ty; i < 32; i += 8)
      t[i][tx] = src[(size_t)(y0 + i) * 1024 + x];
    __syncthreads();
    int n0 = bx * 32;
    for (int i = ty; i < 32; i += 8)
      dst[(size_t)(n0 + i + roff) * dstride + koff + y0 + tx] = (bf16_t)t[tx][i];
  }
}

// ---------------------------------------------------------------- GEMM 256x256 (B^T), merged Q|K epilogue
// r20-validated: 4-phase, pre-barrier ds_reads, 5 barriers/tile.
__global__ __launch_bounds__(512, 2) void gemm256_qk(
    const bf16_t* __restrict__ A, int lda,
    const bf16_t* __restrict__ Bt, int K,
    bf16_t* __restrict__ Qo, bf16_t* __restrict__ Ko, float scale, int nbx)
{
  __shared__ bf16_t As[2][256 * 64];
  __shared__ bf16_t Bs[2][256 * 64];

  const int tid = threadIdx.x;
  const int wave = tid >> 6, lane = tid & 63;
  const int wm = wave >> 2, wn = wave & 3;      // 2 x 4 wave grid
  const int lrow = lane & 15, lch = lane >> 4;

  const int nwg = gridDim.x, cpx = nwg >> 3;
  const int id  = blockIdx.x;
  const int swz = (id & 7) * cpx + (id >> 3);
  const int mb = swz / nbx, nb = swz % nbx;
  const int m0 = mb * 256, n0 = nb * 256;

  const int srow = tid >> 3, spp = tid & 7;     // 64 rows x 8 granules per load

  auto STAGE_A = [&](int buf, int k0, int h) {
#pragma unroll
    for (int i = 0; i < 2; ++i) {
      int r = h * 128 + i * 64 + srow;
      int gsw = (spp ^ (r & 7)) * 8;            // pre-swizzled global source (rule #21)
      gld_lds16(A + (size_t)(m0 + r) * lda + k0 + gsw, &As[buf][r * 64 + spp * 8]);
    }
  };
  auto STAGE_B = [&](int buf, int k0, int h) {
#pragma unroll
    for (int i = 0; i < 2; ++i) {
      int r = h * 128 + i * 64 + srow;
      int gsw = (spp ^ (r & 7)) * 8;
      gld_lds16(Bt + (size_t)(n0 + r) * K + k0 + gsw, &Bs[buf][r * 64 + spp * 8]);
    }
  };

  const int NT = K >> 6;                        // 48 for K=3072
  STAGE_A(0, 0, 0); STAGE_A(0, 0, 1);
  STAGE_B(0, 0, 0); STAGE_B(0, 0, 1);
  STAGE_B(1, 64, 0); STAGE_B(1, 64, 1);
  asm volatile("s_waitcnt vmcnt(4)" ::: "memory");   // tile0 landed; tile1:B in flight
  asm volatile("s_barrier" ::: "memory");

  f32x4 acc[8][4] = {};

  for (int kt = 0; kt < NT; ++kt) {
    const int cur = kt & 1, nxt = cur ^ 1;
    bf16x8 bfr[4][2];                            // B frags, held across all 4 phases

#pragma unroll
    for (int p = 0; p < 4; ++p) {
      bf16x8 af[2][2];
#pragma unroll
      for (int j = 0; j < 2; ++j)
#pragma unroll
        for (int ks = 0; ks < 2; ++ks) {
          int r = wm * 128 + (p * 2 + j) * 16 + lrow;
          af[j][ks] = *(const bf16x8*)&As[cur][r * 64 + (((ks * 4 + lch) ^ (r & 7)) * 8)];
        }
      if (p == 0) {
#pragma unroll
        for (int n = 0; n < 4; ++n)
#pragma unroll
          for (int ks = 0; ks < 2; ++ks) {
            int r = wn * 64 + n * 16 + lrow;
            bfr[n][ks] = *(const bf16x8*)&Bs[cur][r * 64 + (((ks * 4 + lch) ^ (r & 7)) * 8)];
          }
      }
      if (p == 0 && kt + 1 < NT) STAGE_A(nxt, (kt + 1) * 64, 0);
      if (p == 1 && kt + 1 < NT) STAGE_A(nxt, (kt + 1) * 64, 1);
      if (p == 2 && kt + 2 < NT) STAGE_B(cur, (kt + 2) * 64, 0);
      if (p == 3 && kt + 2 < NT) STAGE_B(cur, (kt + 2) * 64, 1);
      if (p == 3) {
        if (kt + 2 < NT)      asm volatile("s_waitcnt vmcnt(4)" ::: "memory");
        else                  asm volatile("s_waitcnt vmcnt(0)" ::: "memory");
      }
      asm volatile("s_barrier" ::: "memory");
      __builtin_amdgcn_s_setprio(1);
#pragma unroll
      for (int ks = 0; ks < 2; ++ks)
#pragma unroll
        for (int j = 0; j < 2; ++j)
#pragma unroll
          for (int n = 0; n < 4; ++n)
            acc[p * 2 + j][n] = __builtin_amdgcn_mfma_f32_16x16x32_bf16(
                af[j][ks], bfr[n][ks], acc[p * 2 + j][n], 0, 0, 0);
      __builtin_amdgcn_s_setprio(0);
      if (p == 3)                                    // only load-bearing barrier2:
        asm volatile("s_barrier" ::: "memory");      // guards next-tile As overwrite
    }
  }

  // epilogue: Q (scaled, cols<1024) / K (cols>=1024) to [B,H,N,D]
  const int g = lane >> 4, cl = lane & 15;
#pragma unroll
  for (int m = 0; m < 8; ++m) {
    int m_base = m0 + wm * 128 + m * 16 + g * 4;
    int bb = m_base >> 11, nn = m_base & 2047;
#pragma unroll
    for (int n = 0; n < 4; ++n) {
      int col = n0 + wn * 64 + n * 16 + cl;
      bf16_t* dst = (col < 1024) ? Qo : Ko;
      int cc2 = col & 1023;
      float sc = (col < 1024) ? scale : 1.0f;
      int h = cc2 >> 6, d = cc2 & 63;
      size_t base = ((size_t)(bb * 16 + h) * 2048 + nn) * 64 + d;
#pragma unroll
      for (int r = 0; r < 4; ++r)
        dst[base + (size_t)r * 64] = (bf16_t)(acc[m][n][r] * sc);
    }
  }
}

// ---------------------------------------------------------------- GEMM 128x256 (B^T), 2-phase pre-barrier (r13-validated)
template<int EPI>
__global__ __launch_bounds__(512, 2) void gemm128x256(
    const bf16_t* __restrict__ A, int lda,
    const bf16_t* __restrict__ Bt, int K,
    void* __restrict__ Cout, const float* __restrict__ bias)
{
  __shared__ bf16_t As[2][128 * 64];
  __shared__ bf16_t Bs[2][256 * 64];

  const int tid = threadIdx.x;
  const int wave = tid >> 6, lane = tid & 63;
  const int wm = wave >> 2, wn = wave & 3;      // 2 x 4 wave grid, per-wave 64x64
  const int lrow = lane & 15, lch = lane >> 4;

  const int nwg = gridDim.x, cpx = nwg >> 3;    // 256 blocks -> cpx=32
  const int id  = blockIdx.x;
  const int swz = (id & 7) * cpx + (id >> 3);
  const int mb = swz >> 2, nb = swz & 3;        // nbx = 4
  const int m0 = mb * 128, n0 = nb * 256;

  const int srow = tid >> 3, spp = tid & 7;

  auto STAGE_A = [&](int buf, int k0, int h) {
    int r = h * 64 + srow;
    int gsw = (spp ^ (r & 7)) * 8;
    gld_lds16(A + (size_t)(m0 + r) * lda + k0 + gsw, &As[buf][r * 64 + spp * 8]);
  };
  auto STAGE_B = [&](int buf, int k0, int h) {
#pragma unroll
    for (int i = 0; i < 2; ++i) {
      int r = h * 128 + i * 64 + srow;
      int gsw = (spp ^ (r & 7)) * 8;
      gld_lds16(Bt + (size_t)(n0 + r) * K + k0 + gsw, &Bs[buf][r * 64 + spp * 8]);
    }
  };

  const int NT = K >> 6;                        // 16 for K=1024
  STAGE_A(0, 0, 0); STAGE_A(0, 0, 1);
  STAGE_B(0, 0, 0); STAGE_B(0, 0, 1);
  STAGE_B(1, 64, 0); STAGE_B(1, 64, 1);
  asm volatile("s_waitcnt vmcnt(4)" ::: "memory");
  asm volatile("s_barrier" ::: "memory");

  f32x4 acc[4][4] = {};

  for (int kt = 0; kt < NT; ++kt) {
    const int cur = kt & 1, nxt = cur ^ 1;
    bf16x8 bfr[4][2];

#pragma unroll
    for (int p = 0; p < 2; ++p) {
      bf16x8 af[2][2];
#pragma unroll
      for (int j = 0; j < 2; ++j)
#pragma unroll
        for (int ks = 0; ks < 2; ++ks) {
          int r = wm * 64 + (p * 2 + j) * 16 + lrow;
          af[j][ks] = *(const bf16x8*)&As[cur][r * 64 + (((ks * 4 + lch) ^ (r & 7)) * 8)];
        }
      if (p == 0) {
#pragma unroll
        for (int n = 0; n < 4; ++n)
#pragma unroll
          for (int ks = 0; ks < 2; ++ks) {
            int r = wn * 64 + n * 16 + lrow;
            bfr[n][ks] = *(const bf16x8*)&Bs[cur][r * 64 + (((ks * 4 + lch) ^ (r & 7)) * 8)];
          }
      }
      if (p == 0 && kt + 1 < NT) { STAGE_A(nxt, (kt + 1) * 64, 0); STAGE_A(nxt, (kt + 1) * 64, 1); }
      if (p == 1 && kt + 2 < NT) { STAGE_B(cur, (kt + 2) * 64, 0); STAGE_B(cur, (kt + 2) * 64, 1); }
      if (p == 1) {
        if (kt + 2 < NT)      asm volatile("s_waitcnt vmcnt(4)" ::: "memory");
        else                  asm volatile("s_waitcnt vmcnt(0)" ::: "memory");
      }
      asm volatile("s_barrier" ::: "memory");
      __builtin_amdgcn_s_setprio(1);
#pragma unroll
      for (int ks = 0; ks < 2; ++ks)
#pragma unroll
        for (int j = 0; j < 2; ++j)
#pragma unroll
          for (int n = 0; n < 4; ++n)
            acc[p * 2 + j][n] = __builtin_amdgcn_mfma_f32_16x16x32_bf16(
                af[j][ks], bfr[n][ks], acc[p * 2 + j][n], 0, 0, 0);
      __builtin_amdgcn_s_setprio(0);
      asm volatile("s_barrier" ::: "memory");
    }
  }

  const int g = lane >> 4, cl = lane & 15;
  if (EPI == 1) {
    bf16_t* Vo = (bf16_t*)Cout;
#pragma unroll
    for (int m = 0; m < 4; ++m) {
      int m_base = m0 + wm * 64 + m * 16 + g * 4;
      int bb = m_base >> 11, nn = m_base & 2047;
#pragma unroll
      for (int n = 0; n < 4; ++n) {
        int col = n0 + wn * 64 + n * 16 + cl;
        int h = col >> 6, d = col & 63;
        ushort4 u;
        u.x = __builtin_bit_cast(unsigned short, (bf16_t)acc[m][n][0]);
        u.y = __builtin_bit_cast(unsigned short, (bf16_t)acc[m][n][1]);
        u.z = __builtin_bit_cast(unsigned short, (bf16_t)acc[m][n][2]);
        u.w = __builtin_bit_cast(unsigned short, (bf16_t)acc[m][n][3]);
        *(ushort4*)(Vo + ((size_t)(bb * 16 + h) * 64 + d) * 2048 + nn) = u;
      }
    }
  } else {
    float* Co = (float*)Cout;
#pragma unroll
    for (int m = 0; m < 4; ++m) {
      int m_base = m0 + wm * 64 + m * 16 + g * 4;
#pragma unroll
      for (int n = 0; n < 4; ++n) {
        int col = n0 + wn * 64 + n * 16 + cl;
        float bv = bias[col];
#pragma unroll
        for (int r = 0; r < 4; ++r)
          Co[(size_t)(m_base + r) * 1024 + col] = acc[m][n][r] + bv;
      }
    }
  }
}

// ---------------------------------------------------------------- attention v5.3 (r19/r20-validated; register-bound floor)
__global__ __launch_bounds__(256, 2) void attn_kernel(
    const bf16_t* __restrict__ Q, const bf16_t* __restrict__ Kb,
    const bf16_t* __restrict__ Vt, bf16_t* __restrict__ O)
{
  __shared__ bf16_t Ks[2][64 * 64];
  __shared__ bf16_t Vs[2][64 * 64];

  const int fid = blockIdx.x;
  const int swz = (fid & 7) * 64 + (fid >> 3);
  const int bh = swz >> 3, qt = swz & 7;
  const int bb = bh >> 4, h = bh & 15;

  const int tid = threadIdx.x, wave = tid >> 6, lane = tid & 63;
  const int lq = lane & 31;
  const int lh = lane >> 5;

  const bf16_t* Qb    = Q  + ((size_t)bh * 2048 + qt * 256) * 64;
  const bf16_t* Kbase = Kb + (size_t)bh * 2048 * 64;
  const bf16_t* Vbase = Vt + (size_t)bh * 64 * 2048;

  const int srow = tid >> 3, spp = tid & 7;      // 32 rows x 8 granules per instr

  auto STAGE_K = [&](int buf, int tile) {
#pragma unroll
    for (int i = 0; i < 2; ++i) {
      int r = i * 32 + srow;
      int sg = (spp ^ (r & 7)) * 8;              // pre-swizzled source (rule #21)
      gld_lds16(Kbase + (size_t)(tile * 64 + r) * 64 + sg, &Ks[buf][i * 2048 + tid * 8]);
    }
  };
  auto STAGE_V = [&](int buf, int tile) {
#pragma unroll
    for (int i = 0; i < 2; ++i) {
      int r = i * 32 + srow;
      int sg = (spp ^ (r & 7)) * 8;
      gld_lds16(Vbase + (size_t)r * 2048 + tile * 64 + sg, &Vs[buf][i * 2048 + tid * 8]);
    }
  };

  // prologue staging: K0, V0, K1 (6 loads)
  STAGE_K(0, 0); STAGE_V(0, 0); STAGE_K(1, 1);

  // Q fragments, two q-blocks per wave (scale*log2e folded into Q buffer)
  bf16x8 qf0[4], qf1[4];
#pragma unroll
  for (int kf = 0; kf < 4; ++kf) {
    qf0[kf] = *(const bf16x8*)(Qb + (size_t)(wave * 64 + lq) * 64 + kf * 16 + lh * 8);
    qf1[kf] = *(const bf16x8*)(Qb + (size_t)(wave * 64 + 32 + lq) * 64 + kf * 16 + lh * 8);
  }

  f32x16 acc0[2] = {}, acc1[2] = {};
  float m0r = -1.0e30f, l0r = 0.f, m1r = -1.0e30f, l1r = 0.f;
  bf16x8 pb0[4], pb1[4];

  auto QKT2 = [&](int tile, f32x16 (&s0)[2], f32x16 (&s1)[2]) {
    const int kb = tile & 1;
#pragma unroll
    for (int nb2 = 0; nb2 < 2; ++nb2) {
      int r = nb2 * 32 + lq;
      f32x16 z0 = {}, z1 = {};
#pragma unroll
      for (int kf = 0; kf < 4; ++kf) {
        bf16x8 ka = *(const bf16x8*)&Ks[kb][r * 64 + (((kf * 2 + lh) ^ (r & 7)) * 8)];
        z0 = __builtin_amdgcn_mfma_f32_32x32x16_bf16(ka, qf0[kf], z0, 0, 0, 0);
        z1 = __builtin_amdgcn_mfma_f32_32x32x16_bf16(ka, qf1[kf], z1, 0, 0, 0);
      }
      s0[nb2] = z0; s1[nb2] = z1;
    }
  };

  auto PV2 = [&](int tile) {
    const int vb = tile & 1;
#pragma unroll
    for (int ks = 0; ks < 4; ++ks)
#pragma unroll
      for (int db = 0; db < 2; ++db) {
        int r = db * 32 + lq;
        bf16x8 va = *(const bf16x8*)&Vs[vb][r * 64 + (((ks * 2 + lh) ^ (r & 7)) * 8)];
        acc0[db] = __builtin_amdgcn_mfma_f32_32x32x16_bf16(va, pb0[ks], acc0[db], 0, 0, 0);
        acc1[db] = __builtin_amdgcn_mfma_f32_32x32x16_bf16(va, pb1[ks], acc1[db], 0, 0, 0);
      }
  };

  auto SOFTMAX = [&](f32x16 (&st)[2], float& mr, float& lr,
                     f32x16 (&ac)[2], bf16x8 (&po)[4]) {
    float tmax = fmaxf(st[0][0], st[0][1]);
#pragma unroll
    for (int nb2 = 0; nb2 < 2; ++nb2)
#pragma unroll
      for (int rg = (nb2 ? 0 : 2); rg < 16; rg += 2)
        tmax = fmaxf(fmaxf(tmax, st[nb2][rg]), st[nb2][rg + 1]);
    tmax = fmaxf(tmax, __shfl_xor(tmax, 32));    // column max (needed per-iter)

    if (!__all(tmax <= mr + 8.0f)) {             // defer-rescale (T13)
      float mnew = fmaxf(mr, tmax);
      float corr = __builtin_amdgcn_exp2f(mr - mnew);
      mr = mnew;
      lr *= corr;
#pragma unroll
      for (int db = 0; db < 2; ++db)
#pragma unroll
        for (int rg = 0; rg < 16; ++rg)
          ac[db][rg] *= corr;
    }

    float sm = 0.f;
#pragma unroll
    for (int nb2 = 0; nb2 < 2; ++nb2)
#pragma unroll
      for (int rg = 0; rg < 16; ++rg) {
        float p = __builtin_amdgcn_exp2f(st[nb2][rg] - mr);
        st[nb2][rg] = p;
        sm += p;
      }
    lr += sm;                                    // per-lane half-row partial;
                                                 // cross-half reduce deferred

    // pack P (T12: cvt_pk + permlane32_swap)
#pragma unroll
    for (int ks = 0; ks < 4; ++ks) {
      const int nb2 = ks >> 1;
      const int R = (ks & 1) * 8;
      unsigned x0, x1, y0, y1;
      asm("v_cvt_pk_bf16_f32 %0, %1, %2" : "=v"(x0) : "v"(st[nb2][R + 0]), "v"(st[nb2][R + 1]));
      asm("v_cvt_pk_bf16_f32 %0, %1, %2" : "=v"(x1) : "v"(st[nb2][R + 2]), "v"(st[nb2][R + 3]));
      asm("v_cvt_pk_bf16_f32 %0, %1, %2" : "=v"(y0) : "v"(st[nb2][R + 4]), "v"(st[nb2][R + 5]));
      asm("v_cvt_pk_bf16_f32 %0, %1, %2" : "=v"(y1) : "v"(st[nb2][R + 6]), "v"(st[nb2][R + 7]));
      asm volatile("v_permlane32_swap_b32 %0, %1" : "+v"(x0), "+v"(y0));
      asm volatile("v_permlane32_swap_b32 %0, %1" : "+v"(x1), "+v"(y1));
      int4 pw;
      pw.x = (int)x0; pw.y = (int)x1; pw.z = (int)y0; pw.w = (int)y1;
      po[ks] = __builtin_bit_cast(bf16x8, pw);
    }
  };

  // prologue compute: S(0) -> softmax -> pb(0); FULL vmcnt drain (r9 lesson)
  asm volatile("s_waitcnt vmcnt(0)" ::: "memory");
  __builtin_amdgcn_s_barrier();
  asm volatile("" ::: "memory");
  {
    f32x16 s0[2], s1[2];
    QKT2(0, s0, s1);
    SOFTMAX(s0, m0r, l0r, acc0, pb0);
    SOFTMAX(s1, m1r, l1r, acc1, pb1);
  }
  asm volatile("s_waitcnt lgkmcnt(0)" ::: "memory");  // my Ks[0] reads done
  __builtin_amdgcn_s_barrier();                       // before iter0 restages Ks[0]
  asm volatile("" ::: "memory");

  for (int t = 0; t < 32; ++t) {
    if (t < 30)       { STAGE_V((t + 1) & 1, t + 1); STAGE_K(t & 1, t + 2); }
    else if (t == 30) { STAGE_V(1, 31); }
    if (t < 30)       asm volatile("s_waitcnt vmcnt(4)" ::: "memory"); // V(t),K(t+1) landed
    else if (t == 30) asm volatile("s_waitcnt vmcnt(2)" ::: "memory");
    else              asm volatile("s_waitcnt vmcnt(0)" ::: "memory");
    __builtin_amdgcn_s_barrier();
    asm volatile("" ::: "memory");

    f32x16 s0[2], s1[2];
    __builtin_amdgcn_s_setprio(1);
    if (t < 31) QKT2(t + 1, s0, s1);   // MFMA, independent of pb
    PV2(t);                            // MFMA, uses pb from previous softmax
    __builtin_amdgcn_s_setprio(0);
    if (t < 31) {
      SOFTMAX(s0, m0r, l0r, acc0, pb0);
      SOFTMAX(s1, m1r, l1r, acc1, pb1);
    }

    asm volatile("s_waitcnt lgkmcnt(0)" ::: "memory");
    __builtin_amdgcn_s_barrier();
    asm volatile("" ::: "memory");
  }

  // epilogue: cross-half sum reduce (once), normalize, write O[B,N,H*D]
  float l0t = l0r + __shfl_xor(l0r, 32);
  float l1t = l1r + __shfl_xor(l1r, 32);
  float inv0 = 1.0f / l0t, inv1 = 1.0f / l1t;
#pragma unroll
  for (int qb = 0; qb < 2; ++qb) {
    float inv = qb ? inv1 : inv0;
    int nn = qt * 256 + wave * 64 + qb * 32 + lq;
    size_t obase = ((size_t)bb * 2048 + nn) * 1024 + h * 64;
#pragma unroll
    for (int db = 0; db < 2; ++db)
#pragma unroll
      for (int rr = 0; rr < 4; ++rr) {
        f32x16& a = qb ? acc1[db] : acc0[db];
        ushort4 u;
        u.x = __builtin_bit_cast(unsigned short, (bf16_t)(a[rr * 4 + 0] * inv));
        u.y = __builtin_bit_cast(unsigned short, (bf16_t)(a[rr * 4 + 1] * inv));
        u.z = __builtin_bit_cast(unsigned short, (bf16_t)(a[rr * 4 + 2] * inv));
        u.w = __builtin_bit_cast(unsigned short, (bf16_t)(a[rr * 4 + 3] * inv));
        *(ushort4*)(O + obase + db * 32 + rr * 8 + lh * 4) = u;
      }
  }
}

// ---------------------------------------------------------------- launch
extern "C" void kernel_launch(void* const* d_in, const int* in_sizes, int n_in,
                              void* d_out, int out_size, void* d_ws, size_t ws_size,
                              hipStream_t stream) {
  const float* words     = (const float*)d_in[0];
  const float* position  = (const float*)d_in[1];
  const float* conscious = (const float*)d_in[2];
  const float* w_wq  = (const float*)d_in[3];
  const float* w_wk  = (const float*)d_in[4];
  const float* w_wv  = (const float*)d_in[5];
  const float* w_pq  = (const float*)d_in[6];
  const float* w_pk  = (const float*)d_in[7];
  const float* w_cq  = (const float*)d_in[8];
  const float* w_ck  = (const float*)d_in[9];
  const float* w_out = (const float*)d_in[10];
  const float* b_out = (const float*)d_in[11];

  char* ws = (char*)d_ws;
  bf16_t* Xcat = (bf16_t*)(ws);                 // 48 MiB [8192][3072]
  bf16_t* Wqkt = (bf16_t*)(ws + 50331648);      // 12 MiB [2048][3072]
  bf16_t* Wvt  = (bf16_t*)(ws + 62914560);      // 2 MiB  [1024][1024]
  bf16_t* Wot  = (bf16_t*)(ws + 65011712);      // 2 MiB  [1024][1024]
  bf16_t* Qb   = (bf16_t*)(ws + 67108864);      // 16 MiB [B,H,N,D]
  bf16_t* Kbf  = (bf16_t*)(ws + 83886080);      // 16 MiB [B,H,N,D]
  bf16_t* Vtb  = (bf16_t*)(ws + 100663296);     // 16 MiB [B,H,D,N]
  bf16_t* Ob   = (bf16_t*)(ws + 117440512);     // 16 MiB [B,N,H*D]

  // fused cast+concat + weight transposes (one dispatch, shared BW)
  prep_kernel<<<32768, 256, 0, stream>>>(words, position, conscious,
      w_wq, w_pq, w_cq, w_wk, w_pk, w_ck, w_wv, w_out, Xcat, Wqkt, Wvt, Wot);

  // merged Q|K GEMM: 256x256 tiles, 32x8 = 256 blocks (1/CU, no tail)
  gemm256_qk<<<256, 512, 0, stream>>>(Xcat, 3072, Wqkt, 3072, Qb, Kbf,
                                      0.125f * 1.44269504f, 8);
  // V GEMM: 128x256 tiles, 64x4 = 256 blocks (words slice of Xcat, K=1024)
  gemm128x256<1><<<256, 512, 0, stream>>>(Xcat, 3072, Wvt, 1024, Vtb, nullptr);

  attn_kernel<<<512, 256, 0, stream>>>(Qb, Kbf, Vtb, Ob);

  // out GEMM: 128x256 tiles, f32 + bias
  gemm128x256<2><<<256, 512, 0, stream>>>(Ob, 1024, Wot, 1024, (float*)d_out, b_out);
}